// Round 13
// baseline (246.697 us; speedup 1.0000x reference)
//
#include <hip/hip_runtime.h>

// Two-pass 3x3 VALID conv:
//  pass 1 (pack_t): x fp32 [16][2048][2048] -> xt bf16 [h][w][16ci] in d_ws
//    via LDS-bounce transpose: contiguous per-plane reads -> [ci][w] LDS ->
//    register EXT-transpose -> contiguous xt writes (R5 layout: ci-half 16B
//    chunks swapped when (w&4)). 32KB LDS, 4 blocks/CU.
//  pass 2 (conv3x3_mfma2): R5-proven conv (~63us): per 32x32 tile stage
//    34x34x16ci via global_load_lds(16B) from xt, 5x mfma_16x16x32_bf16
//    per 16x16 sub-tile. Weight fragments precomputed into d_ws.

#define HIN   2048
#define WIN   2048
#define HOUT  2046
#define WOUT  2046
#define PLANE_IN  (HIN * WIN)
#define PLANE_OUT (HOUT * WOUT)
#define CTR 34
#define CTC 34
#define NCHUNK (CTR * CTC * 2)          // 2312 16B-chunks per conv tile
#define TR 34
#define TC 36                           // fused-fallback staging stride
#define XT_U32 ((size_t)HIN * WIN * 8)  // xt as u32 count (128 MiB)
#define WF_U32 (5 * 64 * 4)

typedef __attribute__((ext_vector_type(8))) short bf16x8;
typedef __attribute__((ext_vector_type(4))) float f32x4;
typedef __attribute__((ext_vector_type(4))) unsigned u32x4;
typedef __attribute__((ext_vector_type(2))) unsigned u32x2;
typedef f32x4 __attribute__((aligned(4))) f32x4_u;

static __device__ __forceinline__ short f2bf(float f) {
    unsigned u = __float_as_uint(f);
    return (short)((u + 0x7FFFu + ((u >> 16) & 1u)) >> 16);   // RNE
}
static __device__ __forceinline__ unsigned pk2(float lo, float hi) {
    unsigned a = __float_as_uint(lo);
    unsigned b = __float_as_uint(hi);
    a = (a + 0x7FFFu + ((a >> 16) & 1u)) >> 16;
    b = (b + 0x7FFFu + ((b >> 16) & 1u)) & 0xFFFF0000u;
    return a | b;
}
// extract u16 #S (0/1) from u32 word
#define EXT16(W, S) ((S) ? ((W) >> 16) : ((W) & 0xFFFFu))

// ---------------- setup: per-lane MFMA weight fragments ----------------------
__global__ __launch_bounds__(64)
void wf_setup(const float* __restrict__ k, unsigned* __restrict__ wfbuf) {
    int lane = threadIdx.x;
    int m = lane & 15, g = lane >> 4;
    #pragma unroll
    for (int i = 0; i < 5; ++i) {
        u32x4 q;
        #pragma unroll
        for (int jj = 0; jj < 4; ++jj) {
            unsigned r = 0;
            #pragma unroll
            for (int e = 0; e < 2; ++e) {
                int kk  = 32 * i + 8 * g + 2 * jj + e;
                int tap = kk >> 4;
                int ci  = kk & 15;
                unsigned v = 0;
                if (tap < 9) v = (unsigned short)f2bf(k[(m * 16 + ci) * 9 + tap]);
                r |= v << (16 * e);
            }
            q[jj] = r;
        }
        *(u32x4*)(wfbuf + (i * 64 + lane) * 4) = q;
    }
}

// ---------------- pass 1: LDS-bounce transpose pack --------------------------
// Block: (h, 1024-w half). Phase 1: ci = tid>>5 reads 8x f32x4 contiguous,
// pk2 -> lds[ci][w] (u32 idx ci*512 + w/2). Phase 2: per thread 2 w-positions,
// 16 ds_read_b32, EXT-transpose, 4x u32x4 contiguous stores in R5 xt layout.
__global__ __launch_bounds__(512, 4)
void pack_t(const float* __restrict__ x, unsigned* __restrict__ xt) {
    __shared__ unsigned lds16[16 * 512];   // 32 KB: [ci][w-pair]

    const int tid = threadIdx.x;
    const int h     = blockIdx.x >> 1;
    const int wbase = (blockIdx.x & 1) << 10;

    // ---- phase 1: contiguous reads, convert, [ci][w] LDS writes ----
    {
        int ci = tid >> 5;
        int wl = (tid & 31) * 4;
        const float* gp = x + (size_t)ci * PLANE_IN + (size_t)h * WIN + wbase;
        #pragma unroll
        for (int j = 0; j < 8; ++j) {
            int w = wl + j * 128;
            f32x4 f = *(const f32x4*)(gp + w);
            u32x2 v;
            v[0] = pk2(f[0], f[1]);
            v[1] = pk2(f[2], f[3]);
            *(u32x2*)&lds16[ci * 512 + (w >> 1)] = v;
        }
    }

    __syncthreads();

    // ---- phase 2: transpose out. Thread owns w2 = tid*2 (2 positions) ----
    {
        int w2 = tid * 2;
        unsigned v[16];
        #pragma unroll
        for (int ci = 0; ci < 16; ++ci)
            v[ci] = lds16[ci * 512 + tid];      // bf16 pair (w2, w2+1) of ci

        int sw = (w2 & 4) ? 4 : 0;              // uniform for w2, w2+1
        unsigned* op = xt + ((size_t)h * WIN + wbase + w2) * 8;
        #pragma unroll
        for (int s = 0; s < 2; ++s) {           // position w2+s
            u32x4 lo, hi;
            #pragma unroll
            for (int p = 0; p < 4; ++p) {
                lo[p] = (EXT16(v[2 * p], s) & 0xFFFFu) | (EXT16(v[2 * p + 1], s) << 16);
                hi[p] = (EXT16(v[2 * p + 8], s) & 0xFFFFu) | (EXT16(v[2 * p + 9], s) << 16);
            }
            *(u32x4*)(op + s * 8 + sw)       = lo;   // ci0-7
            *(u32x4*)(op + s * 8 + (4 - sw)) = hi;   // ci8-15
        }
    }
}

// ---------------- pass 2: MFMA conv (R5-proven, gll from xt) -----------------
__global__ __launch_bounds__(512, 8)
void conv3x3_mfma2(const unsigned* __restrict__ xt,
                   const unsigned* __restrict__ wfbuf,
                   float* __restrict__ out) {
    __shared__ unsigned lds[NCHUNK * 4];   // 36992 B, linear [row][col][ci-chunk]

    const int tid  = threadIdx.x;
    const int lane = tid & 63;
    const int wv   = tid >> 6;
    const int m    = lane & 15;
    const int g    = lane >> 4;

    int bid = blockIdx.x;
    int swz = (bid & 7) * 512 + (bid >> 3);    // XCD-chunked (4096 % 8 == 0)
    int h0 = (swz >> 6) * 32; if (h0 > HOUT - 32) h0 = HOUT - 32;  // 2014
    int w0 = (swz & 63) * 32;

    // ---- stage tile: 2312 chunks of 16B, linear LDS dest, per-lane gsrc ----
    {
        int base = wv * 64;
        #pragma unroll
        for (int pass = 0; pass < 4; ++pass) {
            int c   = pass * 512 + tid;
            int row = (c * 964) >> 16;          // c/68, exact for c<2312
            int sub = c - row * 68;
            int w   = w0 + (sub >> 1); if (w > WIN - 1) w = WIN - 1;
            const unsigned* src = xt + ((size_t)(h0 + row) * WIN + w) * 8 + (sub & 1) * 4;
            __builtin_amdgcn_global_load_lds(
                (const __attribute__((address_space(1))) unsigned*)src,
                (__attribute__((address_space(3))) unsigned*)&lds[(pass * 512 + base) * 4],
                16, 0, 0);
        }
        if (tid < 264) {                        // tail: chunks 2048+tid .. 2311
            int c   = 2048 + tid;
            int row = (c * 964) >> 16;
            int sub = c - row * 68;
            int w   = w0 + (sub >> 1); if (w > WIN - 1) w = WIN - 1;
            const unsigned* src = xt + ((size_t)(h0 + row) * WIN + w) * 8 + (sub & 1) * 4;
            __builtin_amdgcn_global_load_lds(
                (const __attribute__((address_space(1))) unsigned*)src,
                (__attribute__((address_space(3))) unsigned*)&lds[(2048 + base) * 4],
                16, 0, 0);
        }
    }

    // ---- weight fragments: 5 coalesced 16B loads (overlap staging) ----
    bf16x8 wf[5];
    #pragma unroll
    for (int i = 0; i < 5; ++i)
        wf[i] = *(const bf16x8*)(wfbuf + (i * 64 + lane) * 4);

    // ---- per-lane A-fragment LDS byte offsets ----
    int off[5];
    #pragma unroll
    for (int i = 0; i < 5; ++i) {
        int tap = 2 * i + (g >> 1);
        if (tap > 8) tap = 8;                   // dead K (weights are 0)
        int kh = tap / 3;
        int kw = tap - kh * 3;
        int col = m + kw;
        int o = (kh * CTC + col) * 32 + (g & 1) * 16;
        off[i] = o ^ ((col & 4) << 2);          // matches xt pre-swizzle
    }

    __syncthreads();

    const char* ldsb = (const char*)lds;

    #pragma unroll
    for (int hl4 = 0; hl4 < 4; ++hl4) {
        int hl = wv * 4 + hl4;                  // h always < HOUT (h0 <= 2014)
        int h  = h0 + hl;
        #pragma unroll
        for (int nh = 0; nh < 2; ++nh) {
            int wl = nh * 16;
            int tb = (hl * CTC + wl) * 32;
            f32x4 acc = {0.f, 0.f, 0.f, 0.f};
            #pragma unroll
            for (int i = 0; i < 5; ++i) {
                bf16x8 a = *(const bf16x8*)(ldsb + (tb + off[i]));
                acc = __builtin_amdgcn_mfma_f32_16x16x32_bf16(a, wf[i], acc, 0, 0, 0);
            }
            // D: row = g*4+r = spatial, col = m = co  ->  float4 store
            int w = w0 + wl + g * 4;
            float* op = out + m * (size_t)PLANE_OUT + (size_t)h * WOUT + w;
            if (w + 3 < WOUT) {
                *(f32x4_u*)op = acc;
            } else {
                #pragma unroll
                for (int r = 0; r < 4; ++r)
                    if (w + r < WOUT) op[r] = acc[r];
            }
        }
    }
}

// ---------------- fallback A: reg-staged fused (R9, proven 152us total) ------
__global__ __launch_bounds__(512, 8)
void conv3x3_fused(const float* __restrict__ x,
                   const unsigned* __restrict__ wfbuf,
                   float* __restrict__ out) {
    __shared__ unsigned slds[TR * TC * 8];

    const int tid  = threadIdx.x;
    const int lane = tid & 63;
    const int wv   = tid >> 6;
    const int m    = lane & 15;
    const int g    = lane >> 4;

    int bid = blockIdx.x;
    int swz = (bid & 7) * 512 + (bid >> 3);
    int h0 = (swz >> 6) * 32; if (h0 > HOUT - 32) h0 = HOUT - 32;
    int w0 = (swz & 63) * 32;

#define STAGE_TASK(T) do {                                                    \
        int t   = (T);                                                        \
        int q   = t % 9;                                                      \
        int r2  = t / 9;                                                      \
        int cih = r2 & 1;                                                     \
        int row = r2 >> 1;                                                    \
        int c   = 4 * q;                                                      \
        int w   = w0 + c; if (w > WIN - 4) w = WIN - 4;                       \
        const float* gp = x + (size_t)(cih * 8) * PLANE_IN                    \
                            + (size_t)(h0 + row) * WIN + w;                   \
        f32x4 f0 = *(const f32x4*)(gp + 0 * (size_t)PLANE_IN);                \
        f32x4 f1 = *(const f32x4*)(gp + 1 * (size_t)PLANE_IN);                \
        f32x4 f2 = *(const f32x4*)(gp + 2 * (size_t)PLANE_IN);                \
        f32x4 f3 = *(const f32x4*)(gp + 3 * (size_t)PLANE_IN);                \
        f32x4 f4 = *(const f32x4*)(gp + 4 * (size_t)PLANE_IN);                \
        f32x4 f5 = *(const f32x4*)(gp + 5 * (size_t)PLANE_IN);                \
        f32x4 f6 = *(const f32x4*)(gp + 6 * (size_t)PLANE_IN);                \
        f32x4 f7 = *(const f32x4*)(gp + 7 * (size_t)PLANE_IN);                \
        int a = ((row * TC + c) * 32 + cih * 16) ^ ((c & 4) << 2);            \
        u32x4 ch;                                                             \
        ch[0] = pk2(f0[0], f1[0]); ch[1] = pk2(f2[0], f3[0]);                 \
        ch[2] = pk2(f4[0], f5[0]); ch[3] = pk2(f6[0], f7[0]);                 \
        *(u32x4*)((char*)slds + a)      = ch;                                 \
        ch[0] = pk2(f0[1], f1[1]); ch[1] = pk2(f2[1], f3[1]);                 \
        ch[2] = pk2(f4[1], f5[1]); ch[3] = pk2(f6[1], f7[1]);                 \
        *(u32x4*)((char*)slds + a + 32) = ch;                                 \
        ch[0] = pk2(f0[2], f1[2]); ch[1] = pk2(f2[2], f3[2]);                 \
        ch[2] = pk2(f4[2], f5[2]); ch[3] = pk2(f6[2], f7[2]);                 \
        *(u32x4*)((char*)slds + a + 64) = ch;                                 \
        ch[0] = pk2(f0[3], f1[3]); ch[1] = pk2(f2[3], f3[3]);                 \
        ch[2] = pk2(f4[3], f5[3]); ch[3] = pk2(f6[3], f7[3]);                 \
        *(u32x4*)((char*)slds + a + 96) = ch;                                 \
    } while (0)

    STAGE_TASK(tid);
    if (tid < TR * 9 * 2 - 512) STAGE_TASK(512 + tid);
#undef STAGE_TASK

    bf16x8 wf[5];
    #pragma unroll
    for (int i = 0; i < 5; ++i)
        wf[i] = *(const bf16x8*)(wfbuf + (i * 64 + lane) * 4);

    int off[5];
    #pragma unroll
    for (int i = 0; i < 5; ++i) {
        int tap = 2 * i + (g >> 1);
        if (tap > 8) tap = 8;
        int kh = tap / 3;
        int kw = tap - kh * 3;
        int col = m + kw;
        int o = (kh * TC + col) * 32 + (g & 1) * 16;
        off[i] = o ^ ((col & 4) << 2);
    }

    __syncthreads();

    const char* ldsb = (const char*)slds;

    #pragma unroll
    for (int hl4 = 0; hl4 < 4; ++hl4) {
        int hl = wv * 4 + hl4;
        int h  = h0 + hl;
        #pragma unroll
        for (int nh = 0; nh < 2; ++nh) {
            int wl = nh * 16;
            int tb = (hl * TC + wl) * 32;
            f32x4 acc = {0.f, 0.f, 0.f, 0.f};
            #pragma unroll
            for (int i = 0; i < 5; ++i) {
                bf16x8 a = *(const bf16x8*)(ldsb + (tb + off[i]));
                acc = __builtin_amdgcn_mfma_f32_16x16x32_bf16(a, wf[i], acc, 0, 0, 0);
            }
            int w = w0 + wl + g * 4;
            float* op = out + m * (size_t)PLANE_OUT + (size_t)h * WOUT + w;
            if (w + 3 < WOUT) {
                *(f32x4_u*)op = acc;
            } else {
                #pragma unroll
                for (int r = 0; r < 4; ++r)
                    if (w + r < WOUT) op[r] = acc[r];
            }
        }
    }
}

// ---------------- fallback B (no workspace): fp32-staged single pass ---------
__global__ __launch_bounds__(256, 4)
void conv3x3_mfma(const float* __restrict__ x,
                  const float* __restrict__ k,
                  float* __restrict__ out) {
    __shared__ short lds2[TR * 34 * 16];
    const int tid  = threadIdx.x;
    const int lane = tid & 63;
    const int wv   = tid >> 6;
    const int m    = lane & 15;
    const int g    = lane >> 4;
    int bid = blockIdx.x;
    int swz = (bid & 7) * 512 + (bid >> 3);
    int h0 = (swz >> 6) * 32;
    int w0 = (swz & 63) * 32;
    for (int p = tid; p < TR * 34; p += 256) {
        int r = p / 34, c = p - r * 34;
        int hh = h0 + r; if (hh > HIN - 1) hh = HIN - 1;
        int ww = w0 + c; if (ww > WIN - 1) ww = WIN - 1;
        const float* gp = x + hh * WIN + ww;
        short t[16];
        #pragma unroll
        for (int ci = 0; ci < 16; ++ci) t[ci] = f2bf(gp[ci * PLANE_IN]);
        bf16x8 lo, hi;
        #pragma unroll
        for (int j = 0; j < 8; ++j) { lo[j] = t[j]; hi[j] = t[8 + j]; }
        int sw = (c >> 2) & 1;
        bf16x8* dst = (bf16x8*)&lds2[p * 16];
        dst[sw] = lo; dst[1 - sw] = hi;
    }
    bf16x8 wf[5];
    #pragma unroll
    for (int i = 0; i < 5; ++i)
        #pragma unroll
        for (int j = 0; j < 8; ++j) {
            int kk = 32 * i + 8 * g + j;
            int tap = kk >> 4, ci = kk & 15;
            short v = 0;
            if (tap < 9) v = f2bf(k[(m * 16 + ci) * 9 + tap]);
            wf[i][j] = v;
        }
    int off[5];
    #pragma unroll
    for (int i = 0; i < 5; ++i) {
        int tap = 2 * i + (g >> 1);
        if (tap > 8) tap = 8;
        int kh = tap / 3, kw = tap - kh * 3;
        int col = m + kw;
        int o = (kh * 34 + col) * 32 + (g & 1) * 16;
        off[i] = o ^ ((col & 4) << 2);
    }
    __syncthreads();
    const char* ldsb = (const char*)lds2;
    const int coBase = g * 4;
    for (int hl8 = 0; hl8 < 8; ++hl8) {
        int hl = wv * 8 + hl8;
        int h = h0 + hl;
        bool hok = (h < HOUT);
        #pragma unroll
        for (int nh = 0; nh < 2; ++nh) {
            int wl = nh * 16;
            int tb = (hl * 34 + wl) * 32;
            f32x4 acc = {0.f, 0.f, 0.f, 0.f};
            #pragma unroll
            for (int i = 0; i < 5; ++i) {
                bf16x8 b = *(const bf16x8*)(ldsb + (tb + off[i]));
                acc = __builtin_amdgcn_mfma_f32_16x16x32_bf16(wf[i], b, acc, 0, 0, 0);
            }
            int w = w0 + wl + m;
            if (hok && w < WOUT) {
                float* op = out + h * WOUT + w;
                #pragma unroll
                for (int r = 0; r < 4; ++r)
                    op[(coBase + r) * PLANE_OUT] = acc[r];
            }
        }
    }
}

extern "C" void kernel_launch(void* const* d_in, const int* in_sizes, int n_in,
                              void* d_out, int out_size, void* d_ws, size_t ws_size,
                              hipStream_t stream) {
    const float* x = (const float*)d_in[0];
    const float* k = (const float*)d_in[1];
    float* out = (float*)d_out;
    const size_t need = (XT_U32 + WF_U32) * 4;   // 128 MiB xt + 5 KiB wf
    if (ws_size >= need) {
        unsigned* xt = (unsigned*)d_ws;
        unsigned* wfbuf = xt + XT_U32;
        wf_setup<<<dim3(1), dim3(64), 0, stream>>>(k, wfbuf);
        pack_t<<<dim3(4096), dim3(512), 0, stream>>>(x, xt);
        conv3x3_mfma2<<<dim3(4096), dim3(512), 0, stream>>>(xt, wfbuf, out);
    } else if (ws_size >= WF_U32 * 4) {
        unsigned* wfbuf = (unsigned*)d_ws;
        wf_setup<<<dim3(1), dim3(64), 0, stream>>>(k, wfbuf);
        conv3x3_fused<<<dim3(4096), dim3(512), 0, stream>>>(x, wfbuf, out);
    } else {
        conv3x3_mfma<<<dim3(4096), dim3(256), 0, stream>>>(x, k, out);
    }
}

// Round 14
// 173.874 us; speedup vs baseline: 1.4188x; 1.4188x over previous
//
#include <hip/hip_runtime.h>

// Fused single-pass 3x3 VALID conv, gll-fp32 + pipelined LDS-bounce convert.
// x:(16,2048,2048) fp32, k:(16,16,3,3) fp32 -> out:(16,2046,2046) fp32
// Per 32x32 tile:
//   - stage fp32 4-ci slices via global_load_lds into LDS sub-regions A/B,
//     c-order [ci][row][q] (convert reads are lane-linear, conflict-free)
//   - pipelined: STAGE(next slice) fired before CONVERT(current); counted
//     s_waitcnt vmcnt(2) drains only the older slice (<=3 gll instr/slice/thr)
//   - CONVERT: f32x4 read -> pk2 -> ds_write_b64 into bf16 [row][col][ci]
//     region (R8/R9-verified layout, XOR-swizzled on col&4)
//   - compute: 5x mfma_16x16x32_bf16 per 16x16 sub-tile (frozen, verified)
// Weight fragments precomputed once into d_ws.

#define HIN   2048
#define WIN   2048
#define HOUT  2046
#define WOUT  2046
#define PLANE_IN  (HIN * WIN)
#define PLANE_OUT (HOUT * WOUT)
#define TR 34
#define TC 36
#define BF16_U32 (TR * TC * 8)          // 9792 u32 = 39168 B bf16 region
#define SLICE_CH (4 * TR * 9)           // 1224 chunks per 4-ci slice
#define FPA BF16_U32                    // fp32 sub-region A (u32 idx)
#define FPB (BF16_U32 + SLICE_CH * 4)   // fp32 sub-region B
#define LDS_BYTES ((BF16_U32 + 2 * SLICE_CH * 4) * 4)   // 78336 B
#define WF_U32 (5 * 64 * 4)

typedef __attribute__((ext_vector_type(8))) short bf16x8;
typedef __attribute__((ext_vector_type(4))) float f32x4;
typedef __attribute__((ext_vector_type(4))) unsigned u32x4;
typedef __attribute__((ext_vector_type(2))) unsigned u32x2;
typedef f32x4 __attribute__((aligned(4))) f32x4_u;

static __device__ __forceinline__ short f2bf(float f) {
    unsigned u = __float_as_uint(f);
    return (short)((u + 0x7FFFu + ((u >> 16) & 1u)) >> 16);   // RNE
}
static __device__ __forceinline__ unsigned pk2(float lo, float hi) {
    unsigned a = __float_as_uint(lo);
    unsigned b = __float_as_uint(hi);
    a = (a + 0x7FFFu + ((a >> 16) & 1u)) >> 16;
    b = (b + 0x7FFFu + ((b >> 16) & 1u)) & 0xFFFF0000u;
    return a | b;
}

// ---------------- setup: per-lane MFMA weight fragments ----------------------
__global__ __launch_bounds__(64)
void wf_setup(const float* __restrict__ k, unsigned* __restrict__ wfbuf) {
    int lane = threadIdx.x;
    int m = lane & 15, g = lane >> 4;
    #pragma unroll
    for (int i = 0; i < 5; ++i) {
        u32x4 q;
        #pragma unroll
        for (int jj = 0; jj < 4; ++jj) {
            unsigned r = 0;
            #pragma unroll
            for (int e = 0; e < 2; ++e) {
                int kk  = 32 * i + 8 * g + 2 * jj + e;
                int tap = kk >> 4;
                int ci  = kk & 15;
                unsigned v = 0;
                if (tap < 9) v = (unsigned short)f2bf(k[(m * 16 + ci) * 9 + tap]);
                r |= v << (16 * e);
            }
            q[jj] = r;
        }
        *(u32x4*)(wfbuf + (i * 64 + lane) * 4) = q;
    }
}

// ---------------- fused conv: gllb2 ----------------
__global__ __launch_bounds__(512, 4)
void conv3x3_gllb2(const float* __restrict__ x,
                   const unsigned* __restrict__ wfbuf,
                   float* __restrict__ out) {
    extern __shared__ unsigned lds[];

    const int tid  = threadIdx.x;
    const int lane = tid & 63;
    const int wv   = tid >> 6;
    const int m    = lane & 15;
    const int g    = lane >> 4;

    int bid = blockIdx.x;                      // 4096 blocks (64 x 64 tiles)
    int swz = (bid & 7) * 512 + (bid >> 3);    // XCD-chunked (4096 % 8 == 0)
    int h0 = (swz >> 6) * 32; if (h0 > HOUT - 32) h0 = HOUT - 32;  // 2014
    int w0 = (swz & 63) * 32;

    // ---- per-thread stage tasks (slice-invariant): c = ci_l*306 + row*9 + q
    const float* sb[3];
    int du_[3];
    const int nst = (tid < SLICE_CH - 1024) ? 3 : 2;   // 1224 = 2*512 + 200
    #pragma unroll
    for (int p = 0; p < 3; ++p) {
        int c = p * 512 + tid;
        if (c < SLICE_CH) {
            int cil = c / 306;
            int rem = c - cil * 306;
            int row = rem / 9;
            int q   = rem - row * 9;
            int w   = w0 + q * 4; if (w > WIN - 4) w = WIN - 4;
            sb[p]  = x + (size_t)cil * PLANE_IN + (size_t)(h0 + row) * WIN + w;
            du_[p] = (p * 512 + wv * 64) * 4;
        }
    }

#define STAGE(RU, S) do {                                                     \
        _Pragma("unroll")                                                     \
        for (int p = 0; p < 3; ++p) {                                         \
            if (p < nst) {                                                    \
                const float* src = sb[p] + (size_t)(S) * 4 * PLANE_IN;        \
                __builtin_amdgcn_global_load_lds(                             \
                    (const __attribute__((address_space(1))) unsigned*)src,   \
                    (__attribute__((address_space(3))) unsigned*)             \
                        (lds + (RU) + du_[p]),                                \
                    16, 0, 0);                                                \
            }                                                                 \
        }                                                                     \
        __builtin_amdgcn_sched_barrier(0);                                    \
    } while (0)

    // convert slice S (ci 4S..4S+3) from sub-region RU into bf16 region.
    // read j: byte = 16*tid + 4896*j  -> lane-linear, conflict-free.
#define CONVERT(RU, S) do {                                                   \
        if (tid < TR * 9) {                                                   \
            int row = tid / 9;                                                \
            int q   = tid - row * 9;                                          \
            f32x4 v0 = *(const f32x4*)&lds[(RU) + (0 * 306 + tid) * 4];       \
            f32x4 v1 = *(const f32x4*)&lds[(RU) + (1 * 306 + tid) * 4];       \
            f32x4 v2 = *(const f32x4*)&lds[(RU) + (2 * 306 + tid) * 4];       \
            f32x4 v3 = *(const f32x4*)&lds[(RU) + (3 * 306 + tid) * 4];       \
            int c0 = q * 4;                                                   \
            _Pragma("unroll")                                                 \
            for (int cc = 0; cc < 4; ++cc) {                                  \
                int col = c0 + cc;                                            \
                u32x2 t;                                                      \
                t[0] = pk2(v0[cc], v1[cc]);                                   \
                t[1] = pk2(v2[cc], v3[cc]);                                   \
                int a = ((row * TC + col) * 32 + ((S) >> 1) * 16              \
                         + ((S) & 1) * 8) ^ ((col & 4) << 2);                 \
                *(u32x2*)((char*)lds + a) = t;                                \
            }                                                                 \
        }                                                                     \
    } while (0)

#define BAR_FULL() do {                                                       \
        asm volatile("s_waitcnt vmcnt(0) lgkmcnt(0)" ::: "memory");           \
        __builtin_amdgcn_s_barrier();                                         \
        __builtin_amdgcn_sched_barrier(0);                                    \
    } while (0)
#define BAR_VM2() do {                                                        \
        asm volatile("s_waitcnt vmcnt(2) lgkmcnt(0)" ::: "memory");           \
        __builtin_amdgcn_s_barrier();                                         \
        __builtin_amdgcn_sched_barrier(0);                                    \
    } while (0)
#define BAR_LGKM() do {                                                       \
        asm volatile("s_waitcnt lgkmcnt(0)" ::: "memory");                    \
        __builtin_amdgcn_s_barrier();                                         \
        __builtin_amdgcn_sched_barrier(0);                                    \
    } while (0)

    // ---- weight fragments (VMEM loads BEFORE first full drain) ----
    bf16x8 wf[5];
    #pragma unroll
    for (int i = 0; i < 5; ++i)
        wf[i] = *(const bf16x8*)(wfbuf + (i * 64 + lane) * 4);

    // ---- per-lane A-fragment LDS byte offsets (R8/R9-verified) ----
    int off[5];
    #pragma unroll
    for (int i = 0; i < 5; ++i) {
        int tap = 2 * i + (g >> 1);
        if (tap > 8) tap = 8;                   // dead K (weights are 0)
        int kh = tap / 3;
        int kw = tap - kh * 3;
        int col = m + kw;
        int o = (kh * TC + col) * 32 + (g & 1) * 16;
        off[i] = o ^ ((col & 4) << 2);          // matches convert swizzle
    }

    // ---- pipelined stage/convert: slices 0..3 over sub-regions A/B ----
    STAGE(FPA, 0);
    BAR_FULL();                 // slice0 resident (also drains wf loads)
    STAGE(FPB, 1);              // fire slice1
    CONVERT(FPA, 0);
    BAR_LGKM();                 // A readers done (slice1 stays in flight)
    STAGE(FPA, 2);              // fire slice2 into A
    BAR_VM2();                  // drain slice1 (per-thread; barrier joins all)
    CONVERT(FPB, 1);
    BAR_LGKM();                 // B readers done
    STAGE(FPB, 3);              // fire slice3 into B
    BAR_VM2();                  // drain slice2
    CONVERT(FPA, 2);
    BAR_FULL();                 // drain slice3 + A-convert writes
    CONVERT(FPB, 3);
    BAR_LGKM();                 // bf16 tile complete

#undef STAGE
#undef CONVERT
#undef BAR_FULL
#undef BAR_VM2
#undef BAR_LGKM

    // ---- compute (frozen R8/R9 contract) ----
    const char* ldsb = (const char*)lds;

    #pragma unroll
    for (int hl4 = 0; hl4 < 4; ++hl4) {
        int hl = wv * 4 + hl4;                  // h always < HOUT (h0 <= 2014)
        int h  = h0 + hl;
        #pragma unroll
        for (int nh = 0; nh < 2; ++nh) {
            int wl = nh * 16;
            int tb = (hl * TC + wl) * 32;
            f32x4 acc = {0.f, 0.f, 0.f, 0.f};
            #pragma unroll
            for (int i = 0; i < 5; ++i) {
                bf16x8 a = *(const bf16x8*)(ldsb + (tb + off[i]));
                acc = __builtin_amdgcn_mfma_f32_16x16x32_bf16(a, wf[i], acc, 0, 0, 0);
            }
            // D: row = g*4+r = spatial, col = m = co  ->  float4 store
            int w = w0 + wl + g * 4;
            float* op = out + m * (size_t)PLANE_OUT + (size_t)h * WOUT + w;
            if (w + 3 < WOUT) {
                *(f32x4_u*)op = acc;
            } else {
                #pragma unroll
                for (int r = 0; r < 4; ++r)
                    if (w + r < WOUT) op[r] = acc[r];
            }
        }
    }
}

// ---------------- fallback A: reg-staged fused (R9, proven 152us total) ------
__global__ __launch_bounds__(512, 8)
void conv3x3_fused(const float* __restrict__ x,
                   const unsigned* __restrict__ wfbuf,
                   float* __restrict__ out) {
    __shared__ unsigned slds[TR * TC * 8];

    const int tid  = threadIdx.x;
    const int lane = tid & 63;
    const int wv   = tid >> 6;
    const int m    = lane & 15;
    const int g    = lane >> 4;

    int bid = blockIdx.x;
    int swz = (bid & 7) * 512 + (bid >> 3);
    int h0 = (swz >> 6) * 32; if (h0 > HOUT - 32) h0 = HOUT - 32;
    int w0 = (swz & 63) * 32;

#define STAGE_TASK(T) do {                                                    \
        int t   = (T);                                                        \
        int q   = t % 9;                                                      \
        int r2  = t / 9;                                                      \
        int cih = r2 & 1;                                                     \
        int row = r2 >> 1;                                                    \
        int c   = 4 * q;                                                      \
        int w   = w0 + c; if (w > WIN - 4) w = WIN - 4;                       \
        const float* gp = x + (size_t)(cih * 8) * PLANE_IN                    \
                            + (size_t)(h0 + row) * WIN + w;                   \
        f32x4 f0 = *(const f32x4*)(gp + 0 * (size_t)PLANE_IN);                \
        f32x4 f1 = *(const f32x4*)(gp + 1 * (size_t)PLANE_IN);                \
        f32x4 f2 = *(const f32x4*)(gp + 2 * (size_t)PLANE_IN);                \
        f32x4 f3 = *(const f32x4*)(gp + 3 * (size_t)PLANE_IN);                \
        f32x4 f4 = *(const f32x4*)(gp + 4 * (size_t)PLANE_IN);                \
        f32x4 f5 = *(const f32x4*)(gp + 5 * (size_t)PLANE_IN);                \
        f32x4 f6 = *(const f32x4*)(gp + 6 * (size_t)PLANE_IN);                \
        f32x4 f7 = *(const f32x4*)(gp + 7 * (size_t)PLANE_IN);                \
        int a = ((row * TC + c) * 32 + cih * 16) ^ ((c & 4) << 2);            \
        u32x4 ch;                                                             \
        ch[0] = pk2(f0[0], f1[0]); ch[1] = pk2(f2[0], f3[0]);                 \
        ch[2] = pk2(f4[0], f5[0]); ch[3] = pk2(f6[0], f7[0]);                 \
        *(u32x4*)((char*)slds + a)      = ch;                                 \
        ch[0] = pk2(f0[1], f1[1]); ch[1] = pk2(f2[1], f3[1]);                 \
        ch[2] = pk2(f4[1], f5[1]); ch[3] = pk2(f6[1], f7[1]);                 \
        *(u32x4*)((char*)slds + a + 32) = ch;                                 \
        ch[0] = pk2(f0[2], f1[2]); ch[1] = pk2(f2[2], f3[2]);                 \
        ch[2] = pk2(f4[2], f5[2]); ch[3] = pk2(f6[2], f7[2]);                 \
        *(u32x4*)((char*)slds + a + 64) = ch;                                 \
        ch[0] = pk2(f0[3], f1[3]); ch[1] = pk2(f2[3], f3[3]);                 \
        ch[2] = pk2(f4[3], f5[3]); ch[3] = pk2(f6[3], f7[3]);                 \
        *(u32x4*)((char*)slds + a + 96) = ch;                                 \
    } while (0)

    STAGE_TASK(tid);
    if (tid < TR * 9 * 2 - 512) STAGE_TASK(512 + tid);
#undef STAGE_TASK

    bf16x8 wf[5];
    #pragma unroll
    for (int i = 0; i < 5; ++i)
        wf[i] = *(const bf16x8*)(wfbuf + (i * 64 + lane) * 4);

    int off[5];
    #pragma unroll
    for (int i = 0; i < 5; ++i) {
        int tap = 2 * i + (g >> 1);
        if (tap > 8) tap = 8;
        int kh = tap / 3;
        int kw = tap - kh * 3;
        int col = m + kw;
        int o = (kh * TC + col) * 32 + (g & 1) * 16;
        off[i] = o ^ ((col & 4) << 2);
    }

    __syncthreads();

    const char* ldsb = (const char*)slds;

    #pragma unroll
    for (int hl4 = 0; hl4 < 4; ++hl4) {
        int hl = wv * 4 + hl4;
        int h  = h0 + hl;
        #pragma unroll
        for (int nh = 0; nh < 2; ++nh) {
            int wl = nh * 16;
            int tb = (hl * TC + wl) * 32;
            f32x4 acc = {0.f, 0.f, 0.f, 0.f};
            #pragma unroll
            for (int i = 0; i < 5; ++i) {
                bf16x8 a = *(const bf16x8*)(ldsb + (tb + off[i]));
                acc = __builtin_amdgcn_mfma_f32_16x16x32_bf16(a, wf[i], acc, 0, 0, 0);
            }
            int w = w0 + wl + g * 4;
            float* op = out + m * (size_t)PLANE_OUT + (size_t)h * WOUT + w;
            if (w + 3 < WOUT) {
                *(f32x4_u*)op = acc;
            } else {
                #pragma unroll
                for (int r = 0; r < 4; ++r)
                    if (w + r < WOUT) op[r] = acc[r];
            }
        }
    }
}

// ---------------- fallback B (no workspace): fp32-staged single pass ---------
__global__ __launch_bounds__(256, 4)
void conv3x3_mfma(const float* __restrict__ x,
                  const float* __restrict__ k,
                  float* __restrict__ out) {
    __shared__ short lds2[TR * 34 * 16];
    const int tid  = threadIdx.x;
    const int lane = tid & 63;
    const int wv   = tid >> 6;
    const int m    = lane & 15;
    const int g    = lane >> 4;
    int bid = blockIdx.x;
    int swz = (bid & 7) * 512 + (bid >> 3);
    int h0 = (swz >> 6) * 32;
    int w0 = (swz & 63) * 32;
    for (int p = tid; p < TR * 34; p += 256) {
        int r = p / 34, c = p - r * 34;
        int hh = h0 + r; if (hh > HIN - 1) hh = HIN - 1;
        int ww = w0 + c; if (ww > WIN - 1) ww = WIN - 1;
        const float* gp = x + hh * WIN + ww;
        short t[16];
        #pragma unroll
        for (int ci = 0; ci < 16; ++ci) t[ci] = f2bf(gp[ci * PLANE_IN]);
        bf16x8 lo, hi;
        #pragma unroll
        for (int j = 0; j < 8; ++j) { lo[j] = t[j]; hi[j] = t[8 + j]; }
        int sw = (c >> 2) & 1;
        bf16x8* dst = (bf16x8*)&lds2[p * 16];
        dst[sw] = lo; dst[1 - sw] = hi;
    }
    bf16x8 wf[5];
    #pragma unroll
    for (int i = 0; i < 5; ++i)
        #pragma unroll
        for (int j = 0; j < 8; ++j) {
            int kk = 32 * i + 8 * g + j;
            int tap = kk >> 4, ci = kk & 15;
            short v = 0;
            if (tap < 9) v = f2bf(k[(m * 16 + ci) * 9 + tap]);
            wf[i][j] = v;
        }
    int off[5];
    #pragma unroll
    for (int i = 0; i < 5; ++i) {
        int tap = 2 * i + (g >> 1);
        if (tap > 8) tap = 8;
        int kh = tap / 3, kw = tap - kh * 3;
        int col = m + kw;
        int o = (kh * 34 + col) * 32 + (g & 1) * 16;
        off[i] = o ^ ((col & 4) << 2);
    }
    __syncthreads();
    const char* ldsb = (const char*)lds2;
    const int coBase = g * 4;
    for (int hl8 = 0; hl8 < 8; ++hl8) {
        int hl = wv * 8 + hl8;
        int h = h0 + hl;
        bool hok = (h < HOUT);
        #pragma unroll
        for (int nh = 0; nh < 2; ++nh) {
            int wl = nh * 16;
            int tb = (hl * 34 + wl) * 32;
            f32x4 acc = {0.f, 0.f, 0.f, 0.f};
            #pragma unroll
            for (int i = 0; i < 5; ++i) {
                bf16x8 b = *(const bf16x8*)(ldsb + (tb + off[i]));
                acc = __builtin_amdgcn_mfma_f32_16x16x32_bf16(wf[i], b, acc, 0, 0, 0);
            }
            int w = w0 + wl + m;
            if (hok && w < WOUT) {
                float* op = out + h * WOUT + w;
                #pragma unroll
                for (int r = 0; r < 4; ++r)
                    op[(coBase + r) * PLANE_OUT] = acc[r];
            }
        }
    }
}

extern "C" void kernel_launch(void* const* d_in, const int* in_sizes, int n_in,
                              void* d_out, int out_size, void* d_ws, size_t ws_size,
                              hipStream_t stream) {
    const float* x = (const float*)d_in[0];
    const float* k = (const float*)d_in[1];
    float* out = (float*)d_out;
    if (ws_size >= WF_U32 * 4) {
        unsigned* wfbuf = (unsigned*)d_ws;
        wf_setup<<<dim3(1), dim3(64), 0, stream>>>(k, wfbuf);
        hipError_t e = hipFuncSetAttribute(
            reinterpret_cast<const void*>(conv3x3_gllb2),
            hipFuncAttributeMaxDynamicSharedMemorySize, LDS_BYTES);
        if (e == hipSuccess) {
            conv3x3_gllb2<<<dim3(4096), dim3(512), LDS_BYTES, stream>>>(x, wfbuf, out);
        } else {
            conv3x3_fused<<<dim3(4096), dim3(512), 0, stream>>>(x, wfbuf, out);
        }
    } else {
        conv3x3_mfma<<<dim3(4096), dim3(256), 0, stream>>>(x, k, out);
    }
}